// Round 1
// baseline (5164.745 us; speedup 1.0000x reference)
//
#include <hip/hip_runtime.h>
#include <math.h>

#define BATCH 32768
#define D 512
#define NE 8192

#define BM 64
#define BN 64
#define BK 16
#define LDSP 68  // padded float stride for [BK][64] k-major tiles (keeps 16B align, kills write conflicts)

// ---------------- codebook norms ----------------
__global__ void vq_norms_kernel(const float* __restrict__ cb, float* __restrict__ norms) {
    int row  = blockIdx.x * 4 + (threadIdx.x >> 6);   // 4 rows per 256-thread block
    int lane = threadIdx.x & 63;
    const float4* p = (const float4*)(cb + (size_t)row * D);
    float s = 0.f;
#pragma unroll
    for (int i = 0; i < 2; ++i) {                     // 128 float4 per row / 64 lanes
        float4 v = p[lane + 64 * i];
        s += v.x * v.x + v.y * v.y + v.z * v.z + v.w * v.w;
    }
    for (int off = 32; off; off >>= 1) s += __shfl_down(s, off);
    if (lane == 0) norms[row] = s;
}

// ---------------- fused distance + argmin ----------------
__global__ __launch_bounds__(256)
void vq_argmin_kernel(const float* __restrict__ x, const float* __restrict__ cb,
                      const float* __restrict__ norms, int* __restrict__ out_idx) {
    __shared__ float xs[BK * LDSP];
    __shared__ float es[BK * LDSP];
    __shared__ float rv[BM][16];
    __shared__ int   ri[BM][16];

    const int t  = threadIdx.x;
    const int tx = t & 15;          // 16 col groups of 4 entries
    const int ty = t >> 4;          // 16 row groups of 4 rows
    const int row0 = blockIdx.x * BM;
    const int ldrow = t >> 2;       // staging: row/entry 0..63
    const int ldq   = t & 3;        // staging: which float4 of the 16-wide K chunk

    float minv[4];
    int   mini[4];
#pragma unroll
    for (int i = 0; i < 4; ++i) { minv[i] = 3.4e38f; mini[i] = 0; }

    for (int n0 = 0; n0 < NE; n0 += BN) {
        float acc[4][4];
#pragma unroll
        for (int i = 0; i < 4; ++i)
#pragma unroll
            for (int j = 0; j < 4; ++j) acc[i][j] = 0.f;

        for (int kk = 0; kk < D; kk += BK) {
            __syncthreads();
            float4 xv = *(const float4*)&x [(size_t)(row0 + ldrow) * D + kk + ldq * 4];
            float4 ev = *(const float4*)&cb[(size_t)(n0   + ldrow) * D + kk + ldq * 4];
            const float* xvp = (const float*)&xv;
            const float* evp = (const float*)&ev;
#pragma unroll
            for (int j = 0; j < 4; ++j) {
                xs[(ldq * 4 + j) * LDSP + ldrow] = xvp[j];
                es[(ldq * 4 + j) * LDSP + ldrow] = evp[j];
            }
            __syncthreads();
#pragma unroll
            for (int k = 0; k < BK; ++k) {
                float4 xr4 = *(const float4*)&xs[k * LDSP + ty * 4];
                float4 er4 = *(const float4*)&es[k * LDSP + tx * 4];
                const float xr[4] = {xr4.x, xr4.y, xr4.z, xr4.w};
                const float er[4] = {er4.x, er4.y, er4.z, er4.w};
#pragma unroll
                for (int i = 0; i < 4; ++i)
#pragma unroll
                    for (int j = 0; j < 4; ++j)
                        acc[i][j] = fmaf(xr[i], er[j], acc[i][j]);
            }
        }
        // running argmin update (n ascending -> strict < keeps first-min tie rule)
#pragma unroll
        for (int j = 0; j < 4; ++j) {
            int n = n0 + tx * 4 + j;
            float nn = norms[n];
#pragma unroll
            for (int i = 0; i < 4; ++i) {
                float d = fmaf(-2.f, acc[i][j], nn);
                if (d < minv[i]) { minv[i] = d; mini[i] = n; }
            }
        }
    }

    __syncthreads();
#pragma unroll
    for (int i = 0; i < 4; ++i) { rv[ty * 4 + i][tx] = minv[i]; ri[ty * 4 + i][tx] = mini[i]; }
    __syncthreads();
    if (t < BM) {
        float bv = rv[t][0]; int bi = ri[t][0];
#pragma unroll
        for (int j = 1; j < 16; ++j) {
            float v = rv[t][j]; int i2 = ri[t][j];
            if (v < bv || (v == bv && i2 < bi)) { bv = v; bi = i2; }
        }
        out_idx[row0 + t] = bi;
    }
}

// ---------------- gather + STE output + SSE + counts ----------------
__global__ void vq_gather_kernel(const float* __restrict__ x, const float* __restrict__ cb,
                                 const int* __restrict__ idx, float* __restrict__ out,
                                 float* __restrict__ counts, float* __restrict__ sse) {
    const int b    = blockIdx.x;
    const int lane = threadIdx.x;   // 64
    const int e    = idx[b];
    const float4* xp = (const float4*)(x  + (size_t)b * D);
    const float4* qp = (const float4*)(cb + (size_t)e * D);
    float4*       op = (float4*)(out + (size_t)b * D);
    float s = 0.f;
#pragma unroll
    for (int i = 0; i < 2; ++i) {
        float4 xv = xp[lane + 64 * i];
        float4 qv = qp[lane + 64 * i];
        float4 ov;
        float dx = qv.x - xv.x; ov.x = xv.x + dx; s = fmaf(dx, dx, s);
        float dy = qv.y - xv.y; ov.y = xv.y + dy; s = fmaf(dy, dy, s);
        float dz = qv.z - xv.z; ov.z = xv.z + dz; s = fmaf(dz, dz, s);
        float dw = qv.w - xv.w; ov.w = xv.w + dw; s = fmaf(dw, dw, s);
        op[lane + 64 * i] = ov;
    }
    for (int off = 32; off; off >>= 1) s += __shfl_down(s, off);
    if (lane == 0) {
        atomicAdd(sse, s);
        atomicAdd(&counts[e], 1.0f);
    }
}

// ---------------- loss + perplexity ----------------
__global__ void vq_finalize_kernel(const float* __restrict__ counts, const float* __restrict__ sse,
                                   float* __restrict__ out2) {
    __shared__ float red[256];
    float s = 0.f;
    for (int i = threadIdx.x; i < NE; i += 256) {
        float p = counts[i] * (1.0f / (float)BATCH);
        s += p * logf(p + 1e-10f);
    }
    red[threadIdx.x] = s;
    __syncthreads();
    for (int off = 128; off; off >>= 1) {
        if (threadIdx.x < off) red[threadIdx.x] += red[threadIdx.x + off];
        __syncthreads();
    }
    if (threadIdx.x == 0) {
        out2[0] = 1.25f * sse[0] * (1.0f / (float)((size_t)BATCH * D));  // q_loss + 0.25*e_loss
        out2[1] = expf(-red[0]);
    }
}

extern "C" void kernel_launch(void* const* d_in, const int* in_sizes, int n_in,
                              void* d_out, int out_size, void* d_ws, size_t ws_size,
                              hipStream_t stream) {
    const float* x  = (const float*)d_in[0];
    const float* cb = (const float*)d_in[1];
    float* out = (float*)d_out;

    char* ws = (char*)d_ws;
    int*   idx    = (int*)ws;                          // BATCH ints     (128 KB)
    float* norms  = (float*)(ws + BATCH * sizeof(int));// NE floats      (32 KB)
    float* counts = norms + NE;                        // NE floats      (32 KB)
    float* sse    = counts + NE;                       // 1 float

    hipMemsetAsync(counts, 0, (NE + 1) * sizeof(float), stream);
    vq_norms_kernel <<<NE / 4, 256, 0, stream>>>(cb, norms);
    vq_argmin_kernel<<<BATCH / BM, 256, 0, stream>>>(x, cb, norms, idx);
    vq_gather_kernel<<<BATCH, 64, 0, stream>>>(x, cb, idx, out, counts, sse);
    vq_finalize_kernel<<<1, 256, 0, stream>>>(counts, sse, out + (size_t)BATCH * D);
}

// Round 2
// 1486.393 us; speedup vs baseline: 3.4747x; 3.4747x over previous
//
#include <hip/hip_runtime.h>
#include <math.h>

#define BATCH 32768
#define D 512
#define NE 8192
#define NSPLIT 4
#define ESPAN (NE / NSPLIT)   // 2048 entries per split

typedef float  f32x4  __attribute__((ext_vector_type(4)));
typedef short  bf16x8 __attribute__((ext_vector_type(8)));

// ---------------- helpers ----------------
__device__ __forceinline__ void g2l16(const void* g, void* l) {
    __builtin_amdgcn_global_load_lds((const __attribute__((address_space(1))) void*)g,
                                     (__attribute__((address_space(3))) void*)l, 16, 0, 0);
}

__device__ __forceinline__ void split1(float f, unsigned short& h, unsigned short& l) {
    unsigned u = __float_as_uint(f);
    unsigned hu = (u + 0x7FFFu + ((u >> 16) & 1u)) >> 16;   // RNE to bf16
    h = (unsigned short)hu;
    float hf = __uint_as_float(hu << 16);
    float r = f - hf;                                        // exact
    unsigned v = __float_as_uint(r);
    l = (unsigned short)((v + 0x7FFFu + ((v >> 16) & 1u)) >> 16);
}

// ---------------- split fp32 -> bf16 hi/lo ----------------
__global__ void vq_split_kernel(const float* __restrict__ in,
                                unsigned short* __restrict__ hi,
                                unsigned short* __restrict__ lo) {
    size_t i = (size_t)blockIdx.x * 256 + threadIdx.x;   // one 8-float group per thread
    float4 a = ((const float4*)in)[2 * i];
    float4 b = ((const float4*)in)[2 * i + 1];
    unsigned short h[8], l[8];
    split1(a.x, h[0], l[0]); split1(a.y, h[1], l[1]);
    split1(a.z, h[2], l[2]); split1(a.w, h[3], l[3]);
    split1(b.x, h[4], l[4]); split1(b.y, h[5], l[5]);
    split1(b.z, h[6], l[6]); split1(b.w, h[7], l[7]);
    ((ushort4*)hi)[2 * i]     = make_ushort4(h[0], h[1], h[2], h[3]);
    ((ushort4*)hi)[2 * i + 1] = make_ushort4(h[4], h[5], h[6], h[7]);
    ((ushort4*)lo)[2 * i]     = make_ushort4(l[0], l[1], l[2], l[3]);
    ((ushort4*)lo)[2 * i + 1] = make_ushort4(l[4], l[5], l[6], l[7]);
}

// ---------------- codebook norms ----------------
__global__ void vq_norms_kernel(const float* __restrict__ cb, float* __restrict__ norms) {
    int row  = blockIdx.x * 4 + (threadIdx.x >> 6);
    int lane = threadIdx.x & 63;
    const float4* p = (const float4*)(cb + (size_t)row * D);
    float s = 0.f;
#pragma unroll
    for (int i = 0; i < 2; ++i) {
        float4 v = p[lane + 64 * i];
        s += v.x * v.x + v.y * v.y + v.z * v.z + v.w * v.w;
    }
    for (int off = 32; off; off >>= 1) s += __shfl_down(s, off);
    if (lane == 0) norms[row] = s;
}

// ---------------- MFMA distance + top-2 candidates ----------------
// grid = 256 rowblocks * NSPLIT.  block = 256 thr (4 waves), 128 rows x 64-col tiles.
__global__ __launch_bounds__(256, 2)
void vq_mfma_argmin(const unsigned short* __restrict__ xh, const unsigned short* __restrict__ xl,
                    const unsigned short* __restrict__ eh, const unsigned short* __restrict__ el,
                    const float* __restrict__ norms, float4* __restrict__ top2) {
    __shared__ unsigned short lxh[128 * 64];
    __shared__ unsigned short lxl[128 * 64];
    __shared__ unsigned short leh[64 * 64];
    __shared__ unsigned short lel[64 * 64];

    const int t    = threadIdx.x;
    const int w    = t >> 6;
    const int lane = t & 63;
    const int l15  = lane & 15;
    const int l4   = lane >> 4;
    const int rb   = blockIdx.x & 255;
    const int sp   = blockIdx.x >> 8;
    const size_t row0 = (size_t)rb * 128;
    const int nbase = sp * ESPAN;

    float v1[8], v2[8];
    int   i1[8], i2[8];
#pragma unroll
    for (int s = 0; s < 8; ++s) { v1[s] = v2[s] = 3.4e38f; i1[s] = i2[s] = 0x7fffffff; }

    for (int nt = 0; nt < ESPAN / 64; ++nt) {
        const int n0 = nbase + nt * 64;
        float nn[4];
#pragma unroll
        for (int ni = 0; ni < 4; ++ni) nn[ni] = norms[n0 + ni * 16 + l15];

        f32x4 acc[2][4];
#pragma unroll
        for (int mi = 0; mi < 2; ++mi)
#pragma unroll
            for (int ni = 0; ni < 4; ++ni) acc[mi][ni] = (f32x4){0.f, 0.f, 0.f, 0.f};

        for (int kk = 0; kk < D; kk += 64) {
            __syncthreads();   // previous stage's LDS reads done
            // stage x tile: 128 rows x 64 k, hi+lo. 16B chunks; source k-slot pre-swizzled.
#pragma unroll
            for (int i = 0; i < 4; ++i) {
                int c = i * 256 + w * 64 + lane;
                int row = c >> 3, sl = c & 7;
                int ks = sl ^ (row & 7);
                size_t goff = (row0 + row) * D + kk + ks * 8;
                g2l16(xh + goff, lxh + (size_t)(i * 256 + w * 64) * 8);
                g2l16(xl + goff, lxl + (size_t)(i * 256 + w * 64) * 8);
            }
            // stage e tile: 64 entries x 64 k, hi+lo
#pragma unroll
            for (int i = 0; i < 2; ++i) {
                int c = i * 256 + w * 64 + lane;
                int row = c >> 3, sl = c & 7;
                int ks = sl ^ (row & 7);
                size_t goff = (size_t)(n0 + row) * D + kk + ks * 8;
                g2l16(eh + goff, leh + (size_t)(i * 256 + w * 64) * 8);
                g2l16(el + goff, lel + (size_t)(i * 256 + w * 64) * 8);
            }
            __syncthreads();   // compiler emits vmcnt(0) drain before barrier

#pragma unroll
            for (int ks = 0; ks < 2; ++ks) {
                bf16x8 ah[2], al_[2], bh[4], bl[4];
#pragma unroll
                for (int mi = 0; mi < 2; ++mi) {
                    int row = w * 32 + mi * 16 + l15;
                    int off = row * 128 + ((ks * 64 + l4 * 16) ^ ((row & 7) << 4));
                    ah[mi]  = *(const bf16x8*)((const char*)lxh + off);
                    al_[mi] = *(const bf16x8*)((const char*)lxl + off);
                }
#pragma unroll
                for (int ni = 0; ni < 4; ++ni) {
                    int col = ni * 16 + l15;
                    int off = col * 128 + ((ks * 64 + l4 * 16) ^ ((col & 7) << 4));
                    bh[ni] = *(const bf16x8*)((const char*)leh + off);
                    bl[ni] = *(const bf16x8*)((const char*)lel + off);
                }
#pragma unroll
                for (int mi = 0; mi < 2; ++mi)
#pragma unroll
                    for (int ni = 0; ni < 4; ++ni) {
                        acc[mi][ni] = __builtin_amdgcn_mfma_f32_16x16x32_bf16(ah[mi],  bh[ni], acc[mi][ni], 0, 0, 0);
                        acc[mi][ni] = __builtin_amdgcn_mfma_f32_16x16x32_bf16(ah[mi],  bl[ni], acc[mi][ni], 0, 0, 0);
                        acc[mi][ni] = __builtin_amdgcn_mfma_f32_16x16x32_bf16(al_[mi], bh[ni], acc[mi][ni], 0, 0, 0);
                    }
            }
        }
        // epilogue: per row-slot, tile-min over the 4 cols this lane holds, then top-2 update
#pragma unroll
        for (int mi = 0; mi < 2; ++mi)
#pragma unroll
            for (int r = 0; r < 4; ++r) {
                int s = mi * 4 + r;
                float tv = fmaf(-2.f, acc[mi][0][r], nn[0]);
                int   tc = n0 + l15;
#pragma unroll
                for (int ni = 1; ni < 4; ++ni) {
                    float dd = fmaf(-2.f, acc[mi][ni][r], nn[ni]);
                    int   cc = n0 + ni * 16 + l15;
                    if (dd < tv) { tv = dd; tc = cc; }
                }
                bool b1 = tv < v1[s];
                bool b2 = tv < v2[s];
                v2[s] = b1 ? v1[s] : (b2 ? tv : v2[s]);
                i2[s] = b1 ? i1[s] : (b2 ? tc : i2[s]);
                v1[s] = b1 ? tv : v1[s];
                i1[s] = b1 ? tc : i1[s];
            }
    }

    // cross-lane merge over the 16 lanes sharing each row
#pragma unroll
    for (int s = 0; s < 8; ++s) {
#pragma unroll
        for (int off = 1; off < 16; off <<= 1) {
            float a1 = v1[s], a2 = v2[s];
            int   x1 = i1[s], x2 = i2[s];
            float o1 = __shfl_xor(a1, off), o2 = __shfl_xor(a2, off);
            int   p1 = __shfl_xor(x1, off), p2 = __shfl_xor(x2, off);
            bool afirst = (a1 < o1) || (a1 == o1 && x1 < p1);
            float n1 = afirst ? a1 : o1;  int j1 = afirst ? x1 : p1;
            float ca = afirst ? a2 : o2;  int ja = afirst ? x2 : p2;
            float cb = afirst ? o1 : a1;  int jb = afirst ? p1 : x1;
            bool second = (ca < cb) || (ca == cb && ja < jb);
            v1[s] = n1; i1[s] = j1;
            v2[s] = second ? ca : cb; i2[s] = second ? ja : jb;
        }
    }
    if (l15 == 0) {
#pragma unroll
        for (int s = 0; s < 8; ++s) {
            int row = (int)row0 + w * 32 + (s >> 2) * 16 + l4 * 4 + (s & 3);
            top2[(size_t)row * NSPLIT + sp] =
                make_float4(v1[s], __int_as_float(i1[s]), v2[s], __int_as_float(i2[s]));
        }
    }
}

// ---------------- exact fp32 recheck of merged top-2 ----------------
__global__ __launch_bounds__(256)
void vq_recheck(const float* __restrict__ x, const float* __restrict__ cb,
                const float* __restrict__ norms, const float4* __restrict__ top2,
                int* __restrict__ out_idx) {
    const int w = threadIdx.x >> 6, lane = threadIdx.x & 63;
    const int row = blockIdx.x * 4 + w;

    float bv1 = 3.4e38f, bv2 = 3.4e38f;
    int   bi1 = 0x7fffffff, bi2 = 0x7fffffff;
#pragma unroll
    for (int sp = 0; sp < NSPLIT; ++sp) {
        float4 tp = top2[(size_t)row * NSPLIT + sp];
        float av[2] = {tp.x, tp.z};
        int   ai[2] = {__float_as_int(tp.y), __float_as_int(tp.w)};
#pragma unroll
        for (int q = 0; q < 2; ++q) {
            bool b1 = (av[q] < bv1) || (av[q] == bv1 && ai[q] < bi1);
            bool b2 = (av[q] < bv2) || (av[q] == bv2 && ai[q] < bi2);
            bv2 = b1 ? bv1 : (b2 ? av[q] : bv2);
            bi2 = b1 ? bi1 : (b2 ? ai[q] : bi2);
            bv1 = b1 ? av[q] : bv1;
            bi1 = b1 ? ai[q] : bi1;
        }
    }
    const float4* xp = (const float4*)(x + (size_t)row * D);
    float4 xa = xp[lane * 2], xb = xp[lane * 2 + 1];
    int cand[2] = {bi1, bi2};
    float d[2];
#pragma unroll
    for (int c = 0; c < 2; ++c) {
        const float4* ep = (const float4*)(cb + (size_t)cand[c] * D);
        float4 ea = ep[lane * 2], eb = ep[lane * 2 + 1];
        float s = 0.f;
        s = fmaf(xa.x, ea.x, s); s = fmaf(xa.y, ea.y, s);
        s = fmaf(xa.z, ea.z, s); s = fmaf(xa.w, ea.w, s);
        s = fmaf(xb.x, eb.x, s); s = fmaf(xb.y, eb.y, s);
        s = fmaf(xb.z, eb.z, s); s = fmaf(xb.w, eb.w, s);
#pragma unroll
        for (int off = 1; off < 64; off <<= 1) s += __shfl_xor(s, off);
        d[c] = fmaf(-2.f, s, norms[cand[c]]);
    }
    bool first = (d[0] < d[1]) || (d[0] == d[1] && cand[0] < cand[1]);
    if (lane == 0) out_idx[row] = first ? cand[0] : cand[1];
}

// ---------------- fallback fp32 argmin (round-1, known-good) ----------------
#define BM 64
#define BN 64
#define BK 16
#define LDSP 68
__global__ __launch_bounds__(256)
void vq_argmin_kernel(const float* __restrict__ x, const float* __restrict__ cb,
                      const float* __restrict__ norms, int* __restrict__ out_idx) {
    __shared__ float xs[BK * LDSP];
    __shared__ float es[BK * LDSP];
    __shared__ float rv[BM][16];
    __shared__ int   ri[BM][16];

    const int t  = threadIdx.x;
    const int tx = t & 15;
    const int ty = t >> 4;
    const int row0 = blockIdx.x * BM;
    const int ldrow = t >> 2;
    const int ldq   = t & 3;

    float minv[4];
    int   mini[4];
#pragma unroll
    for (int i = 0; i < 4; ++i) { minv[i] = 3.4e38f; mini[i] = 0; }

    for (int n0 = 0; n0 < NE; n0 += BN) {
        float acc[4][4];
#pragma unroll
        for (int i = 0; i < 4; ++i)
#pragma unroll
            for (int j = 0; j < 4; ++j) acc[i][j] = 0.f;

        for (int kk = 0; kk < D; kk += BK) {
            __syncthreads();
            float4 xv = *(const float4*)&x [(size_t)(row0 + ldrow) * D + kk + ldq * 4];
            float4 ev = *(const float4*)&cb[(size_t)(n0   + ldrow) * D + kk + ldq * 4];
            const float* xvp = (const float*)&xv;
            const float* evp = (const float*)&ev;
#pragma unroll
            for (int j = 0; j < 4; ++j) {
                xs[(ldq * 4 + j) * LDSP + ldrow] = xvp[j];
                es[(ldq * 4 + j) * LDSP + ldrow] = evp[j];
            }
            __syncthreads();
#pragma unroll
            for (int k = 0; k < BK; ++k) {
                float4 xr4 = *(const float4*)&xs[k * LDSP + ty * 4];
                float4 er4 = *(const float4*)&es[k * LDSP + tx * 4];
                const float xr[4] = {xr4.x, xr4.y, xr4.z, xr4.w};
                const float er[4] = {er4.x, er4.y, er4.z, er4.w};
#pragma unroll
                for (int i = 0; i < 4; ++i)
#pragma unroll
                    for (int j = 0; j < 4; ++j)
                        acc[i][j] = fmaf(xr[i], er[j], acc[i][j]);
            }
        }
#pragma unroll
        for (int j = 0; j < 4; ++j) {
            int n = n0 + tx * 4 + j;
            float nnv = norms[n];
#pragma unroll
            for (int i = 0; i < 4; ++i) {
                float dd = fmaf(-2.f, acc[i][j], nnv);
                if (dd < minv[i]) { minv[i] = dd; mini[i] = n; }
            }
        }
    }
    __syncthreads();
#pragma unroll
    for (int i = 0; i < 4; ++i) { rv[ty * 4 + i][tx] = minv[i]; ri[ty * 4 + i][tx] = mini[i]; }
    __syncthreads();
    if (t < BM) {
        float bv = rv[t][0]; int bi = ri[t][0];
#pragma unroll
        for (int j = 1; j < 16; ++j) {
            float v = rv[t][j]; int i2_ = ri[t][j];
            if (v < bv || (v == bv && i2_ < bi)) { bv = v; bi = i2_; }
        }
        out_idx[row0 + t] = bi;
    }
}

// ---------------- gather + STE output + SSE + counts ----------------
__global__ void vq_gather_kernel(const float* __restrict__ x, const float* __restrict__ cb,
                                 const int* __restrict__ idx, float* __restrict__ out,
                                 float* __restrict__ counts, float* __restrict__ sse) {
    const int b    = blockIdx.x;
    const int lane = threadIdx.x;
    const int e    = idx[b];
    const float4* xp = (const float4*)(x  + (size_t)b * D);
    const float4* qp = (const float4*)(cb + (size_t)e * D);
    float4*       op = (float4*)(out + (size_t)b * D);
    float s = 0.f;
#pragma unroll
    for (int i = 0; i < 2; ++i) {
        float4 xv = xp[lane + 64 * i];
        float4 qv = qp[lane + 64 * i];
        float4 ov;
        float dx = qv.x - xv.x; ov.x = xv.x + dx; s = fmaf(dx, dx, s);
        float dy = qv.y - xv.y; ov.y = xv.y + dy; s = fmaf(dy, dy, s);
        float dz = qv.z - xv.z; ov.z = xv.z + dz; s = fmaf(dz, dz, s);
        float dw = qv.w - xv.w; ov.w = xv.w + dw; s = fmaf(dw, dw, s);
        op[lane + 64 * i] = ov;
    }
    for (int off = 32; off; off >>= 1) s += __shfl_down(s, off);
    if (lane == 0) {
        atomicAdd(sse, s);
        atomicAdd(&counts[e], 1.0f);
    }
}

// ---------------- loss + perplexity ----------------
__global__ void vq_finalize_kernel(const float* __restrict__ counts, const float* __restrict__ sse,
                                   float* __restrict__ out2) {
    __shared__ float red[256];
    float s = 0.f;
    for (int i = threadIdx.x; i < NE; i += 256) {
        float p = counts[i] * (1.0f / (float)BATCH);
        s += p * logf(p + 1e-10f);
    }
    red[threadIdx.x] = s;
    __syncthreads();
    for (int off = 128; off; off >>= 1) {
        if (threadIdx.x < off) red[threadIdx.x] += red[threadIdx.x + off];
        __syncthreads();
    }
    if (threadIdx.x == 0) {
        out2[0] = 1.25f * sse[0] * (1.0f / (float)((size_t)BATCH * D));
        out2[1] = expf(-red[0]);
    }
}

extern "C" void kernel_launch(void* const* d_in, const int* in_sizes, int n_in,
                              void* d_out, int out_size, void* d_ws, size_t ws_size,
                              hipStream_t stream) {
    const float* x  = (const float*)d_in[0];
    const float* cb = (const float*)d_in[1];
    float* out = (float*)d_out;

    char* ws = (char*)d_ws;
    // layout (256B-aligned regions)
    int*    idx    = (int*)ws;                               // 128 KB
    float*  norms  = (float*)(ws + 131072);                  // 32 KB
    float*  counts = (float*)(ws + 163840);                  // 32 KB
    float*  sse    = (float*)(ws + 196608);                  // 256 B
    float4* top2   = (float4*)(ws + 196864);                 // 2 MB
    unsigned short* xh = (unsigned short*)(ws + 2294016);    // 32 MB
    unsigned short* xl = (unsigned short*)(ws + 35848448);   // 32 MB
    unsigned short* ehp = (unsigned short*)(ws + 69402880);  // 8 MB
    unsigned short* elp = (unsigned short*)(ws + 77791488);  // 8 MB
    const size_t WS_NEED = 86180096;

    hipMemsetAsync(counts, 0, 33024, stream);  // counts + sse
    vq_norms_kernel<<<NE / 4, 256, 0, stream>>>(cb, norms);

    if (ws_size >= WS_NEED) {
        vq_split_kernel<<<(BATCH * D / 8) / 256, 256, 0, stream>>>(x, xh, xl);
        vq_split_kernel<<<(NE * D / 8) / 256, 256, 0, stream>>>(cb, ehp, elp);
        vq_mfma_argmin<<<256 * NSPLIT, 256, 0, stream>>>(xh, xl, ehp, elp, norms, top2);
        vq_recheck<<<BATCH / 4, 256, 0, stream>>>(x, cb, norms, top2, idx);
    } else {
        vq_argmin_kernel<<<BATCH / BM, 256, 0, stream>>>(x, cb, norms, idx);
    }
    vq_gather_kernel<<<BATCH, 64, 0, stream>>>(x, cb, idx, out, counts, sse);
    vq_finalize_kernel<<<1, 256, 0, stream>>>(counts, sse, out + (size_t)BATCH * D);
}

// Round 3
// 1149.179 us; speedup vs baseline: 4.4943x; 1.2934x over previous
//
#include <hip/hip_runtime.h>
#include <math.h>

#define BATCH 32768
#define D 512
#define NE 8192
#define NSPLIT 4
#define ESPAN (NE / NSPLIT)   // 2048 entries per split
#define MARGIN 1.6e-2f        // ~60 sigma of fp16 distance error

typedef float    f32x4 __attribute__((ext_vector_type(4)));
typedef _Float16 f16x8 __attribute__((ext_vector_type(8)));

__device__ __forceinline__ void g2l16(const void* g, void* l) {
    __builtin_amdgcn_global_load_lds((const __attribute__((address_space(1))) void*)g,
                                     (__attribute__((address_space(3))) void*)l, 16, 0, 0);
}
__device__ __forceinline__ unsigned short f2h(float f) {
    union { _Float16 h; unsigned short u; } c; c.h = (_Float16)f; return c.u;
}

// ---------------- fp32 -> fp16 ----------------
__global__ void vq_tof16_kernel(const float* __restrict__ in, unsigned short* __restrict__ out) {
    size_t i = (size_t)blockIdx.x * 256 + threadIdx.x;   // 8 floats per thread
    float4 a = ((const float4*)in)[2 * i];
    float4 b = ((const float4*)in)[2 * i + 1];
    ((ushort4*)out)[2 * i]     = make_ushort4(f2h(a.x), f2h(a.y), f2h(a.z), f2h(a.w));
    ((ushort4*)out)[2 * i + 1] = make_ushort4(f2h(b.x), f2h(b.y), f2h(b.z), f2h(b.w));
}

// ---------------- codebook norms (exact fp32) ----------------
__global__ void vq_norms_kernel(const float* __restrict__ cb, float* __restrict__ norms) {
    int row  = blockIdx.x * 4 + (threadIdx.x >> 6);
    int lane = threadIdx.x & 63;
    const float4* p = (const float4*)(cb + (size_t)row * D);
    float s = 0.f;
#pragma unroll
    for (int i = 0; i < 2; ++i) {
        float4 v = p[lane + 64 * i];
        s += v.x * v.x + v.y * v.y + v.z * v.z + v.w * v.w;
    }
    for (int off = 32; off; off >>= 1) s += __shfl_down(s, off);
    if (lane == 0) norms[row] = s;
}

// ---------------- fp16 MFMA distance + top-4 candidates per split ----------------
// grid = 256 rowblocks * NSPLIT. block = 256 thr (4 waves), 128 rows x 64-entry tiles.
__global__ __launch_bounds__(256, 2)
void vq_f16_topk(const unsigned short* __restrict__ xq, const unsigned short* __restrict__ eq,
                 const float* __restrict__ norms, float2* __restrict__ cands) {
    __shared__ char arena[24576];
    unsigned short* xs = (unsigned short*)arena;            // 128x64 f16 = 16 KB
    unsigned short* es = (unsigned short*)(arena + 16384);  // 64x64  f16 =  8 KB

    const int t    = threadIdx.x;
    const int w    = t >> 6;
    const int lane = t & 63;
    const int l15  = lane & 15;
    const int l4   = lane >> 4;
    const int rb   = blockIdx.x & 255;
    const int sp   = blockIdx.x >> 8;
    const size_t row0 = (size_t)rb * 128;
    const int nbase = sp * ESPAN;

    // per-lane top-2 over this lane's column subset (col % 16 == l15), per row-slot
    float v1[8], v2[8];
    int   i1[8], i2[8];
#pragma unroll
    for (int s = 0; s < 8; ++s) { v1[s] = v2[s] = 3.4e38f; i1[s] = i2[s] = 0x7fffffff; }

    for (int nt = 0; nt < ESPAN / 64; ++nt) {
        const int n0 = nbase + nt * 64;
        float nn[4];
#pragma unroll
        for (int ni = 0; ni < 4; ++ni) nn[ni] = norms[n0 + ni * 16 + l15];

        f32x4 acc[2][4];
#pragma unroll
        for (int mi = 0; mi < 2; ++mi)
#pragma unroll
            for (int ni = 0; ni < 4; ++ni) acc[mi][ni] = (f32x4){0.f, 0.f, 0.f, 0.f};

        for (int kk = 0; kk < D; kk += 64) {
            __syncthreads();
            // stage x tile: 128 rows x 64 k fp16; linear LDS dest, XOR-preswizzled source k-slot
#pragma unroll
            for (int i = 0; i < 4; ++i) {
                int c = i * 256 + w * 64 + lane;
                int row = c >> 3, sl = c & 7;
                int ks = sl ^ (row & 7);
                g2l16(xq + (row0 + row) * D + kk + ks * 8, xs + (size_t)(i * 256 + w * 64) * 8);
            }
            // stage e tile: 64 entries x 64 k fp16
#pragma unroll
            for (int i = 0; i < 2; ++i) {
                int c = i * 256 + w * 64 + lane;
                int row = c >> 3, sl = c & 7;
                int ks = sl ^ (row & 7);
                g2l16(eq + (size_t)(n0 + row) * D + kk + ks * 8, es + (size_t)(i * 256 + w * 64) * 8);
            }
            __syncthreads();

#pragma unroll
            for (int ks = 0; ks < 2; ++ks) {
                f16x8 a[2], b[4];
#pragma unroll
                for (int mi = 0; mi < 2; ++mi) {
                    int row = w * 32 + mi * 16 + l15;
                    int off = row * 128 + ((ks * 64 + l4 * 16) ^ ((row & 7) << 4));
                    a[mi] = *(const f16x8*)((const char*)xs + off);
                }
#pragma unroll
                for (int ni = 0; ni < 4; ++ni) {
                    int col = ni * 16 + l15;
                    int off = col * 128 + ((ks * 64 + l4 * 16) ^ ((col & 7) << 4));
                    b[ni] = *(const f16x8*)((const char*)es + off);
                }
#pragma unroll
                for (int mi = 0; mi < 2; ++mi)
#pragma unroll
                    for (int ni = 0; ni < 4; ++ni)
                        acc[mi][ni] = __builtin_amdgcn_mfma_f32_16x16x32_f16(a[mi], b[ni], acc[mi][ni], 0, 0, 0);
            }
        }
        // epilogue: per-entry top-2 update (NO tile-min first — near-ties in the same
        // lane-subset must both survive; candidate-loss analysis depends on it)
#pragma unroll
        for (int mi = 0; mi < 2; ++mi)
#pragma unroll
            for (int r = 0; r < 4; ++r) {
                int s = mi * 4 + r;
#pragma unroll
                for (int ni = 0; ni < 4; ++ni) {
                    float dd = fmaf(-2.f, acc[mi][ni][r], nn[ni]);
                    int   cc = n0 + ni * 16 + l15;
                    if (dd < v2[s]) {             // cc ascending -> strict < keeps lowest index on ties
                        bool b1 = dd < v1[s];
                        v2[s] = b1 ? v1[s] : dd; i2[s] = b1 ? i1[s] : cc;
                        v1[s] = b1 ? dd : v1[s]; i1[s] = b1 ? cc : i1[s];
                    }
                }
            }
    }

    // selection: 32 (v,i) per row in LDS -> top-4 by (v, idx); two 64-row passes (16 KB reuse)
    float2* sel = (float2*)arena;   // [64][16][2]
#pragma unroll 1
    for (int p = 0; p < 2; ++p) {
        __syncthreads();
        if ((w >> 1) == p) {
#pragma unroll
            for (int s = 0; s < 8; ++s) {
                int rl = (w & 1) * 32 + (s >> 2) * 16 + l4 * 4 + (s & 3);
                sel[(rl * 16 + l15) * 2 + 0] = make_float2(v1[s], __int_as_float(i1[s]));
                sel[(rl * 16 + l15) * 2 + 1] = make_float2(v2[s], __int_as_float(i2[s]));
            }
        }
        __syncthreads();
        if (t < 64) {
            float tv[4] = {3.4e38f, 3.4e38f, 3.4e38f, 3.4e38f};
            int   ti[4] = {0x7fffffff, 0x7fffffff, 0x7fffffff, 0x7fffffff};
            for (int j = 0; j < 32; ++j) {
                float2 e = sel[t * 32 + j];
                float v = e.x; int ix = __float_as_int(e.y);
#pragma unroll
                for (int q = 0; q < 4; ++q) {
                    if (v < tv[q] || (v == tv[q] && ix < ti[q])) {
#pragma unroll
                        for (int z = 3; z > q; --z) { tv[z] = tv[z - 1]; ti[z] = ti[z - 1]; }
                        tv[q] = v; ti[q] = ix;
                        break;
                    }
                }
            }
            size_t grow = row0 + p * 64 + t;
#pragma unroll
            for (int q = 0; q < 4; ++q)
                cands[grow * 16 + sp * 4 + q] = make_float2(tv[q], __int_as_float(ti[q]));
        }
    }
}

// ---------------- exact fp32 rescoring of the 16 candidates ----------------
__global__ __launch_bounds__(256)
void vq_recheck16(const float* __restrict__ x, const float* __restrict__ cb,
                  const float* __restrict__ norms, const float2* __restrict__ cands,
                  int* __restrict__ out_idx) {
    const int w = threadIdx.x >> 6, lane = threadIdx.x & 63;
    const int row = blockIdx.x * 4 + w;

    const float4* xp = (const float4*)(x + (size_t)row * D);
    float4 xa = xp[lane * 2], xb = xp[lane * 2 + 1];

    float cv[16]; int ci[16];
    float amin = 3.4e38f;
    const float2* cp = cands + (size_t)row * 16;
#pragma unroll
    for (int c = 0; c < 16; ++c) {
        float2 f = cp[c];
        cv[c] = f.x; ci[c] = __float_as_int(f.y);
        amin = fminf(amin, cv[c]);
    }
    float bd = 3.4e38f; int bi = 0x7fffffff;
#pragma unroll 1
    for (int c = 0; c < 16; ++c) {
        if (cv[c] <= amin + MARGIN) {     // uniform across the wave
            const float4* ep = (const float4*)(cb + (size_t)ci[c] * D);
            float4 ea = ep[lane * 2], eb = ep[lane * 2 + 1];
            float s = 0.f;
            s = fmaf(xa.x, ea.x, s); s = fmaf(xa.y, ea.y, s);
            s = fmaf(xa.z, ea.z, s); s = fmaf(xa.w, ea.w, s);
            s = fmaf(xb.x, eb.x, s); s = fmaf(xb.y, eb.y, s);
            s = fmaf(xb.z, eb.z, s); s = fmaf(xb.w, eb.w, s);
#pragma unroll
            for (int off = 1; off < 64; off <<= 1) s += __shfl_xor(s, off);
            float dd = fmaf(-2.f, s, norms[ci[c]]);
            if (dd < bd || (dd == bd && ci[c] < bi)) { bd = dd; bi = ci[c]; }
        }
    }
    if (lane == 0) out_idx[row] = bi;
}

// ---------------- fallback fp32 argmin (round-1, known-good) ----------------
#define BM 64
#define BN 64
#define BK 16
#define LDSP 68
__global__ __launch_bounds__(256)
void vq_argmin_kernel(const float* __restrict__ x, const float* __restrict__ cb,
                      const float* __restrict__ norms, int* __restrict__ out_idx) {
    __shared__ float xs[BK * LDSP];
    __shared__ float es[BK * LDSP];
    __shared__ float rv[BM][16];
    __shared__ int   ri[BM][16];

    const int t  = threadIdx.x;
    const int tx = t & 15;
    const int ty = t >> 4;
    const int row0 = blockIdx.x * BM;
    const int ldrow = t >> 2;
    const int ldq   = t & 3;

    float minv[4];
    int   mini[4];
#pragma unroll
    for (int i = 0; i < 4; ++i) { minv[i] = 3.4e38f; mini[i] = 0; }

    for (int n0 = 0; n0 < NE; n0 += BN) {
        float acc[4][4];
#pragma unroll
        for (int i = 0; i < 4; ++i)
#pragma unroll
            for (int j = 0; j < 4; ++j) acc[i][j] = 0.f;

        for (int kk = 0; kk < D; kk += BK) {
            __syncthreads();
            float4 xv = *(const float4*)&x [(size_t)(row0 + ldrow) * D + kk + ldq * 4];
            float4 ev = *(const float4*)&cb[(size_t)(n0   + ldrow) * D + kk + ldq * 4];
            const float* xvp = (const float*)&xv;
            const float* evp = (const float*)&ev;
#pragma unroll
            for (int j = 0; j < 4; ++j) {
                xs[(ldq * 4 + j) * LDSP + ldrow] = xvp[j];
                es[(ldq * 4 + j) * LDSP + ldrow] = evp[j];
            }
            __syncthreads();
#pragma unroll
            for (int k = 0; k < BK; ++k) {
                float4 xr4 = *(const float4*)&xs[k * LDSP + ty * 4];
                float4 er4 = *(const float4*)&es[k * LDSP + tx * 4];
                const float xr[4] = {xr4.x, xr4.y, xr4.z, xr4.w};
                const float er[4] = {er4.x, er4.y, er4.z, er4.w};
#pragma unroll
                for (int i = 0; i < 4; ++i)
#pragma unroll
                    for (int j = 0; j < 4; ++j)
                        acc[i][j] = fmaf(xr[i], er[j], acc[i][j]);
            }
        }
#pragma unroll
        for (int j = 0; j < 4; ++j) {
            int n = n0 + tx * 4 + j;
            float nnv = norms[n];
#pragma unroll
            for (int i = 0; i < 4; ++i) {
                float dd = fmaf(-2.f, acc[i][j], nnv);
                if (dd < minv[i]) { minv[i] = dd; mini[i] = n; }
            }
        }
    }
    __syncthreads();
#pragma unroll
    for (int i = 0; i < 4; ++i) { rv[ty * 4 + i][tx] = minv[i]; ri[ty * 4 + i][tx] = mini[i]; }
    __syncthreads();
    if (t < BM) {
        float bv = rv[t][0]; int bi = ri[t][0];
#pragma unroll
        for (int j = 1; j < 16; ++j) {
            float v = rv[t][j]; int i2_ = ri[t][j];
            if (v < bv || (v == bv && i2_ < bi)) { bv = v; bi = i2_; }
        }
        out_idx[row0 + t] = bi;
    }
}

// ---------------- gather + STE output + SSE + counts ----------------
__global__ void vq_gather_kernel(const float* __restrict__ x, const float* __restrict__ cb,
                                 const int* __restrict__ idx, float* __restrict__ out,
                                 float* __restrict__ counts, float* __restrict__ sse) {
    const int b    = blockIdx.x;
    const int lane = threadIdx.x;
    const int e    = idx[b];
    const float4* xp = (const float4*)(x  + (size_t)b * D);
    const float4* qp = (const float4*)(cb + (size_t)e * D);
    float4*       op = (float4*)(out + (size_t)b * D);
    float s = 0.f;
#pragma unroll
    for (int i = 0; i < 2; ++i) {
        float4 xv = xp[lane + 64 * i];
        float4 qv = qp[lane + 64 * i];
        float4 ov;
        float dx = qv.x - xv.x; ov.x = xv.x + dx; s = fmaf(dx, dx, s);
        float dy = qv.y - xv.y; ov.y = xv.y + dy; s = fmaf(dy, dy, s);
        float dz = qv.z - xv.z; ov.z = xv.z + dz; s = fmaf(dz, dz, s);
        float dw = qv.w - xv.w; ov.w = xv.w + dw; s = fmaf(dw, dw, s);
        op[lane + 64 * i] = ov;
    }
    for (int off = 32; off; off >>= 1) s += __shfl_down(s, off);
    if (lane == 0) {
        atomicAdd(sse, s);
        atomicAdd(&counts[e], 1.0f);
    }
}

// ---------------- loss + perplexity ----------------
__global__ void vq_finalize_kernel(const float* __restrict__ counts, const float* __restrict__ sse,
                                   float* __restrict__ out2) {
    __shared__ float red[256];
    float s = 0.f;
    for (int i = threadIdx.x; i < NE; i += 256) {
        float p = counts[i] * (1.0f / (float)BATCH);
        s += p * logf(p + 1e-10f);
    }
    red[threadIdx.x] = s;
    __syncthreads();
    for (int off = 128; off; off >>= 1) {
        if (threadIdx.x < off) red[threadIdx.x] += red[threadIdx.x + off];
        __syncthreads();
    }
    if (threadIdx.x == 0) {
        out2[0] = 1.25f * sse[0] * (1.0f / (float)((size_t)BATCH * D));
        out2[1] = expf(-red[0]);
    }
}

extern "C" void kernel_launch(void* const* d_in, const int* in_sizes, int n_in,
                              void* d_out, int out_size, void* d_ws, size_t ws_size,
                              hipStream_t stream) {
    const float* x  = (const float*)d_in[0];
    const float* cb = (const float*)d_in[1];
    float* out = (float*)d_out;

    char* ws = (char*)d_ws;
    int*    idx    = (int*)ws;                              // 128 KB  @ 0
    float*  norms  = (float*)(ws + 131072);                 // 32 KB
    float*  counts = (float*)(ws + 163840);                 // 32 KB
    float*  sse    = (float*)(ws + 196608);                 // 256 B
    float2* cands  = (float2*)(ws + 196864);                // 4 MB   (32768 x 16 x 8B)
    unsigned short* xq = (unsigned short*)(ws + 4391168);   // 32 MB  fp16 x
    unsigned short* eq = (unsigned short*)(ws + 37945600);  // 8 MB   fp16 codebook
    const size_t WS_NEED = 46334208;

    hipMemsetAsync(counts, 0, 33024, stream);  // counts + sse
    vq_norms_kernel<<<NE / 4, 256, 0, stream>>>(cb, norms);

    if (ws_size >= WS_NEED) {
        vq_tof16_kernel<<<(BATCH * D / 8) / 256, 256, 0, stream>>>(x, xq);
        vq_tof16_kernel<<<(NE * D / 8) / 256, 256, 0, stream>>>(cb, eq);
        vq_f16_topk<<<256 * NSPLIT, 256, 0, stream>>>(xq, eq, norms, cands);
        vq_recheck16<<<BATCH / 4, 256, 0, stream>>>(x, cb, norms, cands, idx);
    } else {
        vq_argmin_kernel<<<BATCH / BM, 256, 0, stream>>>(x, cb, norms, idx);
    }
    vq_gather_kernel<<<BATCH, 64, 0, stream>>>(x, cb, idx, out, counts, sse);
    vq_finalize_kernel<<<1, 256, 0, stream>>>(counts, sse, out + (size_t)BATCH * D);
}

// Round 4
// 443.457 us; speedup vs baseline: 11.6466x; 2.5914x over previous
//
#include <hip/hip_runtime.h>
#include <math.h>

#define BATCH 32768
#define D 512
#define NE 8192
#define NSPLIT 4
#define ESPAN (NE / NSPLIT)   // 2048 entries per split
#define NT 64                 // entries per tile
#define KC 128                // k per chunk (4 chunks over D)
#define MARGIN 1.6e-2f        // ~27 sigma of fp16 distance error (proven round 3)

typedef float    f32x4 __attribute__((ext_vector_type(4)));
typedef _Float16 f16x8 __attribute__((ext_vector_type(8)));

__device__ __forceinline__ void g2l16(const void* g, void* l) {
    __builtin_amdgcn_global_load_lds((const __attribute__((address_space(1))) void*)g,
                                     (__attribute__((address_space(3))) void*)l, 16, 0, 0);
}
__device__ __forceinline__ unsigned short f2h(float f) {
    union { _Float16 h; unsigned short u; } c; c.h = (_Float16)f; return c.u;
}

// ---------------- codebook norms (exact fp32) ----------------
__global__ void vq_norms_kernel(const float* __restrict__ cb, float* __restrict__ norms) {
    int row  = blockIdx.x * 4 + (threadIdx.x >> 6);
    int lane = threadIdx.x & 63;
    const float4* p = (const float4*)(cb + (size_t)row * D);
    float s = 0.f;
#pragma unroll
    for (int i = 0; i < 2; ++i) {
        float4 v = p[lane + 64 * i];
        s += v.x * v.x + v.y * v.y + v.z * v.z + v.w * v.w;
    }
    for (int off = 32; off; off >>= 1) s += __shfl_down(s, off);
    if (lane == 0) norms[row] = s;
}

// ---------------- codebook fp32 -> fp16, XOR-pre-swizzled for LDS staging ----------------
// LDS[row][slot] must hold original k-granule (slot ^ (row&15)); involution -> write src
// granule g to slot (g&15)^(n&15) within its 16-granule chunk.
__global__ void vq_cvt_swz(const float* __restrict__ cb, unsigned short* __restrict__ eq) {
    int i = blockIdx.x * 256 + threadIdx.x;       // granule id (8 f16), NE*64 total
    int n = i >> 6, g = i & 63;
    int ch = g >> 4;
    int sl = (g & 15) ^ (n & 15);
    const float4* sp = (const float4*)(cb + (size_t)n * D + g * 8);
    float4 a = sp[0], b = sp[1];
    ushort4* dp = (ushort4*)(eq + (size_t)n * D + ch * KC + sl * 8);
    dp[0] = make_ushort4(f2h(a.x), f2h(a.y), f2h(a.z), f2h(a.w));
    dp[1] = make_ushort4(f2h(b.x), f2h(b.y), f2h(b.z), f2h(b.w));
}

// ---------------- fp16 MFMA distance, x-in-registers, per-lane top-2 ----------------
// grid 512 = (8 XCD lanes) x 64; block 512 thr (8 waves) = 256 rows x ESPAN entries.
__global__ __launch_bounds__(512, 2)
void vq_topk2(const float* __restrict__ x, const unsigned short* __restrict__ eq,
              const float* __restrict__ norms, float4* __restrict__ cands) {
    __shared__ unsigned short es[2][NT * KC];   // 2 x 16 KB double buffer

    const int t = threadIdx.x;
    const int w = t >> 6, lane = t & 63, l15 = lane & 15, l4 = lane >> 4;
    const int b = blockIdx.x;
    const int xcd = b & 7;                       // same-split blocks share an XCD's L2
    const int sp  = xcd >> 1;
    const int rb  = ((xcd & 1) << 6) | (b >> 3);
    const size_t row0 = (size_t)rb * 256;
    const int nbase = sp * ESPAN;

    // ---- prologue: A fragments for this wave's 32 rows, full D, fused f32->f16 ----
    f16x8 af[2][16];
#pragma unroll
    for (int mi = 0; mi < 2; ++mi) {
        const float4* xp = (const float4*)(x + (row0 + w * 32 + mi * 16 + l15) * D);
#pragma unroll
        for (int ks = 0; ks < 16; ++ks) {
            float4 p0 = xp[ks * 8 + l4 * 2];
            float4 p1 = xp[ks * 8 + l4 * 2 + 1];
            f16x8 v;
            v[0] = (_Float16)p0.x; v[1] = (_Float16)p0.y;
            v[2] = (_Float16)p0.z; v[3] = (_Float16)p0.w;
            v[4] = (_Float16)p1.x; v[5] = (_Float16)p1.y;
            v[6] = (_Float16)p1.z; v[7] = (_Float16)p1.w;
            af[mi][ks] = v;
        }
    }

    float v1[8], v2[8];
    int   i1[8], i2[8];
#pragma unroll
    for (int s = 0; s < 8; ++s) { v1[s] = v2[s] = 3.4e38f; i1[s] = i2[s] = 0x7fffffff; }

    // staging: 16 KB chunk, 512 thr x 32 B (2 x g2l16); linear LDS dest, source pre-swizzled
#define STAGE(BUFI, STEP) do {                                                          \
        const int snt_ = (STEP) >> 2, sch_ = (STEP) & 3;                                \
        const int nb_ = nbase + snt_ * NT;                                              \
        _Pragma("unroll")                                                               \
        for (int i_ = 0; i_ < 2; ++i_) {                                                \
            int c_ = i_ * 512 + t;                                                      \
            int row_ = c_ >> 4, sl_ = c_ & 15;                                          \
            g2l16(eq + (size_t)(nb_ + row_) * D + sch_ * KC + sl_ * 8,                  \
                  &es[BUFI][(i_ * 512 + w * 64) * 8]);                                  \
        }                                                                               \
    } while (0)

    STAGE(0, 0);
    __syncthreads();            // compiler drains vmcnt(0) before barrier
    int buf = 0;

    for (int nt = 0; nt < ESPAN / NT; ++nt) {   // 32 entry tiles
        const int n0 = nbase + nt * NT;
        f32x4 acc[2][4];
#pragma unroll
        for (int mi = 0; mi < 2; ++mi)
#pragma unroll
            for (int ni = 0; ni < 4; ++ni) acc[mi][ni] = (f32x4){0.f, 0.f, 0.f, 0.f};

#pragma unroll
        for (int ch = 0; ch < 4; ++ch) {
            const int step = nt * 4 + ch + 1;
            if (step < (ESPAN / NT) * 4) STAGE(buf ^ 1, step);   // prefetch in flight over MFMA
            const char* esp = (const char*)es[buf];
#pragma unroll
            for (int ksb = 0; ksb < 4; ++ksb) {
                f16x8 bfr[4];
#pragma unroll
                for (int ni = 0; ni < 4; ++ni) {
                    int slot = ((ksb << 2) | l4) ^ l15;          // XOR de-swizzle on read
                    bfr[ni] = *(const f16x8*)(esp + ni * 4096 + l15 * 256 + slot * 16);
                }
#pragma unroll
                for (int mi = 0; mi < 2; ++mi)
#pragma unroll
                    for (int ni = 0; ni < 4; ++ni)
                        acc[mi][ni] = __builtin_amdgcn_mfma_f32_16x16x32_f16(
                            af[mi][ch * 4 + ksb], bfr[ni], acc[mi][ni], 0, 0, 0);
            }
            __syncthreads();    // drains staged loads (vmcnt) + ds reads (lgkm)
            buf ^= 1;
        }

        // per-entry top-2 update (no tile-min: same-lane near-ties must both survive)
        float nn[4];
#pragma unroll
        for (int ni = 0; ni < 4; ++ni) nn[ni] = norms[n0 + ni * 16 + l15];
#pragma unroll
        for (int mi = 0; mi < 2; ++mi)
#pragma unroll
            for (int r = 0; r < 4; ++r) {
                int s = mi * 4 + r;
#pragma unroll
                for (int ni = 0; ni < 4; ++ni) {
                    float dd = fmaf(-2.f, acc[mi][ni][r], nn[ni]);
                    int   cc = n0 + ni * 16 + l15;
                    if (dd < v2[s]) {
                        bool b1 = dd < v1[s];
                        v2[s] = b1 ? v1[s] : dd; i2[s] = b1 ? i1[s] : cc;
                        v1[s] = b1 ? dd : v1[s]; i1[s] = b1 ? cc : i1[s];
                    }
                }
            }
    }
#undef STAGE

    // raw per-lane top-2 out: cands[row][sp*16 + l15] = (v1,i1,v2,i2)
#pragma unroll
    for (int s = 0; s < 8; ++s) {
        int mi = s >> 2, r = s & 3;
        size_t rowc = row0 + w * 32 + mi * 16 + l4 * 4 + r;
        cands[rowc * 64 + sp * 16 + l15] =
            make_float4(v1[s], __int_as_float(i1[s]), v2[s], __int_as_float(i2[s]));
    }
}

// ---------------- fused: merge cands + exact rescore + STE out + loss partials ----------------
__global__ __launch_bounds__(512)
void vq_finish(const float* __restrict__ x, const float* __restrict__ cb,
               const float* __restrict__ norms, const float4* __restrict__ cands,
               float* __restrict__ counts, float* __restrict__ psum, float* __restrict__ out) {
    __shared__ float red[8];
    const int t = threadIdx.x, w = t >> 6, lane = t & 63;
    const size_t row = (size_t)blockIdx.x * 8 + w;

    float4 c4 = cands[row * 64 + lane];
    float va = c4.x, vb = c4.z;
    int   ia = __float_as_int(c4.y), ib = __float_as_int(c4.w);
    float m = fminf(va, vb);
#pragma unroll
    for (int off = 1; off < 64; off <<= 1) m = fminf(m, __shfl_xor(m, off));
    const float thr = m + MARGIN;

    const float4* xp = (const float4*)(x + row * D);
    float4 xa = xp[lane * 2], xb = xp[lane * 2 + 1];

    float bd = 3.4e38f; int bi = 0x7fffffff;
#pragma unroll 1
    for (int q = 0; q < 2; ++q) {
        unsigned long long mk = __ballot((q == 0 ? va : vb) <= thr);
        while (mk) {
            int src = __builtin_ctzll(mk);
            mk &= mk - 1;
            int ci = __shfl(q == 0 ? ia : ib, src);
            const float4* ep = (const float4*)(cb + (size_t)ci * D);
            float4 ea = ep[lane * 2], eb = ep[lane * 2 + 1];
            float s = 0.f;
            s = fmaf(xa.x, ea.x, s); s = fmaf(xa.y, ea.y, s);
            s = fmaf(xa.z, ea.z, s); s = fmaf(xa.w, ea.w, s);
            s = fmaf(xb.x, eb.x, s); s = fmaf(xb.y, eb.y, s);
            s = fmaf(xb.z, eb.z, s); s = fmaf(xb.w, eb.w, s);
#pragma unroll
            for (int off = 1; off < 64; off <<= 1) s += __shfl_xor(s, off);
            float dd = fmaf(-2.f, s, norms[ci]);
            if (dd < bd || (dd == bd && ci < bi)) { bd = dd; bi = ci; }
        }
    }

    // STE output + SSE partial (identical arithmetic to rounds 1-3: o = x + (q - x))
    const float4* qp = (const float4*)(cb + (size_t)bi * D);
    float4 qa = qp[lane * 2], qb = qp[lane * 2 + 1];
    float4* op = (float4*)(out + row * D);
    float s2 = 0.f;
    float4 oa, ob;
    {
        float d0 = qa.x - xa.x; oa.x = xa.x + d0; s2 = fmaf(d0, d0, s2);
        float d1 = qa.y - xa.y; oa.y = xa.y + d1; s2 = fmaf(d1, d1, s2);
        float d2 = qa.z - xa.z; oa.z = xa.z + d2; s2 = fmaf(d2, d2, s2);
        float d3 = qa.w - xa.w; oa.w = xa.w + d3; s2 = fmaf(d3, d3, s2);
        float d4 = qb.x - xb.x; ob.x = xb.x + d4; s2 = fmaf(d4, d4, s2);
        float d5 = qb.y - xb.y; ob.y = xb.y + d5; s2 = fmaf(d5, d5, s2);
        float d6 = qb.z - xb.z; ob.z = xb.z + d6; s2 = fmaf(d6, d6, s2);
        float d7 = qb.w - xb.w; ob.w = xb.w + d7; s2 = fmaf(d7, d7, s2);
    }
    op[lane * 2] = oa; op[lane * 2 + 1] = ob;
    for (int off = 32; off; off >>= 1) s2 += __shfl_down(s2, off);
    if (lane == 0) {
        red[w] = s2;
        atomicAdd(&counts[bi], 1.0f);    // scattered over 8192 addrs — OK
    }
    __syncthreads();
    if (t == 0) {
        float s = 0.f;
#pragma unroll
        for (int i = 0; i < 8; ++i) s += red[i];
        psum[blockIdx.x] = s;            // no same-address atomics
    }
}

// ---------------- loss + perplexity ----------------
__global__ void vq_finalize_kernel(const float* __restrict__ counts, const float* __restrict__ psum,
                                   float* __restrict__ out2) {
    __shared__ float rede[256];
    __shared__ float reds[256];
    float se = 0.f, ss = 0.f;
    for (int i = threadIdx.x; i < NE; i += 256) {
        float p = counts[i] * (1.0f / (float)BATCH);
        se += p * logf(p + 1e-10f);
    }
    for (int i = threadIdx.x; i < 4096; i += 256) ss += psum[i];
    rede[threadIdx.x] = se; reds[threadIdx.x] = ss;
    __syncthreads();
    for (int off = 128; off; off >>= 1) {
        if (threadIdx.x < off) {
            rede[threadIdx.x] += rede[threadIdx.x + off];
            reds[threadIdx.x] += reds[threadIdx.x + off];
        }
        __syncthreads();
    }
    if (threadIdx.x == 0) {
        out2[0] = 1.25f * reds[0] * (1.0f / (float)((size_t)BATCH * D));
        out2[1] = expf(-rede[0]);
    }
}

// ---------------- fallback fp32 path (round-1, known-good) ----------------
#define BM 64
#define BN 64
#define BK 16
#define LDSP 68
__global__ __launch_bounds__(256)
void vq_argmin_kernel(const float* __restrict__ x, const float* __restrict__ cb,
                      const float* __restrict__ norms, int* __restrict__ out_idx) {
    __shared__ float xs[BK * LDSP];
    __shared__ float es[BK * LDSP];
    __shared__ float rv[BM][16];
    __shared__ int   ri[BM][16];
    const int t = threadIdx.x, tx = t & 15, ty = t >> 4;
    const int row0 = blockIdx.x * BM, ldrow = t >> 2, ldq = t & 3;
    float minv[4]; int mini[4];
#pragma unroll
    for (int i = 0; i < 4; ++i) { minv[i] = 3.4e38f; mini[i] = 0; }
    for (int n0 = 0; n0 < NE; n0 += BN) {
        float acc[4][4];
#pragma unroll
        for (int i = 0; i < 4; ++i)
#pragma unroll
            for (int j = 0; j < 4; ++j) acc[i][j] = 0.f;
        for (int kk = 0; kk < D; kk += BK) {
            __syncthreads();
            float4 xv = *(const float4*)&x [(size_t)(row0 + ldrow) * D + kk + ldq * 4];
            float4 ev = *(const float4*)&cb[(size_t)(n0   + ldrow) * D + kk + ldq * 4];
            const float* xvp = (const float*)&xv;
            const float* evp = (const float*)&ev;
#pragma unroll
            for (int j = 0; j < 4; ++j) {
                xs[(ldq * 4 + j) * LDSP + ldrow] = xvp[j];
                es[(ldq * 4 + j) * LDSP + ldrow] = evp[j];
            }
            __syncthreads();
#pragma unroll
            for (int k = 0; k < BK; ++k) {
                float4 xr4 = *(const float4*)&xs[k * LDSP + ty * 4];
                float4 er4 = *(const float4*)&es[k * LDSP + tx * 4];
                const float xr[4] = {xr4.x, xr4.y, xr4.z, xr4.w};
                const float er[4] = {er4.x, er4.y, er4.z, er4.w};
#pragma unroll
                for (int i = 0; i < 4; ++i)
#pragma unroll
                    for (int j = 0; j < 4; ++j)
                        acc[i][j] = fmaf(xr[i], er[j], acc[i][j]);
            }
        }
#pragma unroll
        for (int j = 0; j < 4; ++j) {
            int n = n0 + tx * 4 + j;
            float nnv = norms[n];
#pragma unroll
            for (int i = 0; i < 4; ++i) {
                float dd = fmaf(-2.f, acc[i][j], nnv);
                if (dd < minv[i]) { minv[i] = dd; mini[i] = n; }
            }
        }
    }
    __syncthreads();
#pragma unroll
    for (int i = 0; i < 4; ++i) { rv[ty * 4 + i][tx] = minv[i]; ri[ty * 4 + i][tx] = mini[i]; }
    __syncthreads();
    if (t < BM) {
        float bv = rv[t][0]; int bi = ri[t][0];
#pragma unroll
        for (int j = 1; j < 16; ++j) {
            float v = rv[t][j]; int iz = ri[t][j];
            if (v < bv || (v == bv && iz < bi)) { bv = v; bi = iz; }
        }
        out_idx[row0 + t] = bi;
    }
}

__global__ void vq_gather_kernel(const float* __restrict__ x, const float* __restrict__ cb,
                                 const int* __restrict__ idx, float* __restrict__ out,
                                 float* __restrict__ counts, float* __restrict__ psum) {
    const int b = blockIdx.x, lane = threadIdx.x;
    const int e = idx[b];
    const float4* xp = (const float4*)(x  + (size_t)b * D);
    const float4* qp = (const float4*)(cb + (size_t)e * D);
    float4*       op = (float4*)(out + (size_t)b * D);
    float s = 0.f;
#pragma unroll
    for (int i = 0; i < 2; ++i) {
        float4 xv = xp[lane + 64 * i];
        float4 qv = qp[lane + 64 * i];
        float4 ov;
        float dx = qv.x - xv.x; ov.x = xv.x + dx; s = fmaf(dx, dx, s);
        float dy = qv.y - xv.y; ov.y = xv.y + dy; s = fmaf(dy, dy, s);
        float dz = qv.z - xv.z; ov.z = xv.z + dz; s = fmaf(dz, dz, s);
        float dw = qv.w - xv.w; ov.w = xv.w + dw; s = fmaf(dw, dw, s);
        op[lane + 64 * i] = ov;
    }
    for (int off = 32; off; off >>= 1) s += __shfl_down(s, off);
    if (lane == 0) {
        atomicAdd(&psum[0], s);
        atomicAdd(&counts[e], 1.0f);
    }
}

extern "C" void kernel_launch(void* const* d_in, const int* in_sizes, int n_in,
                              void* d_out, int out_size, void* d_ws, size_t ws_size,
                              hipStream_t stream) {
    const float* x  = (const float*)d_in[0];
    const float* cb = (const float*)d_in[1];
    float* out = (float*)d_out;

    char* ws = (char*)d_ws;
    float*  norms  = (float*)ws;                             // 32 KB @ 0
    float*  counts = (float*)(ws + 32768);                   // 32 KB
    float*  psum   = (float*)(ws + 65536);                   // 16 KB (4096 partials)
    int*    idx    = (int*)(ws + 81920);                     // 128 KB (fallback only)
    float4* cands  = (float4*)(ws + 262144);                 // 32 MB (32768 x 64 x 16B)
    unsigned short* eq = (unsigned short*)(ws + 33816576);   // 8 MB fp16 swizzled codebook
    const size_t WS_NEED = 42205184;

    hipMemsetAsync(counts, 0, NE * sizeof(float), stream);
    vq_norms_kernel<<<NE / 4, 256, 0, stream>>>(cb, norms);

    if (ws_size >= WS_NEED) {
        vq_cvt_swz<<<NE * 64 / 256, 256, 0, stream>>>(cb, eq);
        vq_topk2<<<512, 512, 0, stream>>>(x, eq, norms, cands);
        vq_finish<<<BATCH / 8, 512, 0, stream>>>(x, cb, norms, cands, counts, psum, out);
    } else {
        hipMemsetAsync(psum, 0, 4096 * sizeof(float), stream);
        vq_argmin_kernel<<<BATCH / BM, 256, 0, stream>>>(x, cb, norms, idx);
        vq_gather_kernel<<<BATCH, 64, 0, stream>>>(x, cb, idx, out, counts, psum);
    }
    vq_finalize_kernel<<<1, 256, 0, stream>>>(counts, psum, out + (size_t)BATCH * D);
}

// Round 5
// 424.799 us; speedup vs baseline: 12.1581x; 1.0439x over previous
//
#include <hip/hip_runtime.h>
#include <math.h>

#define BATCH 32768
#define D 512
#define NE 8192
#define NSPLIT 4
#define ESPAN (NE / NSPLIT)   // 2048 entries per split
#define NT 64                 // entries per tile
#define KC 128                // k per chunk (4 chunks over D)
#define NPHASE ((ESPAN / NT) * 4)   // 128
#define MARGIN 1.6e-2f        // ~27 sigma of fp16 distance error (proven rounds 3-4)

typedef float    f32x4 __attribute__((ext_vector_type(4)));
typedef _Float16 f16x8 __attribute__((ext_vector_type(8)));

__device__ __forceinline__ void g2l16(const void* g, void* l) {
    __builtin_amdgcn_global_load_lds((const __attribute__((address_space(1))) void*)g,
                                     (__attribute__((address_space(3))) void*)l, 16, 0, 0);
}
__device__ __forceinline__ unsigned short f2h(float f) {
    union { _Float16 h; unsigned short u; } c; c.h = (_Float16)f; return c.u;
}

// ---------------- codebook norms (exact fp32) ----------------
__global__ void vq_norms_kernel(const float* __restrict__ cb, float* __restrict__ norms) {
    int row  = blockIdx.x * 4 + (threadIdx.x >> 6);
    int lane = threadIdx.x & 63;
    const float4* p = (const float4*)(cb + (size_t)row * D);
    float s = 0.f;
#pragma unroll
    for (int i = 0; i < 2; ++i) {
        float4 v = p[lane + 64 * i];
        s += v.x * v.x + v.y * v.y + v.z * v.z + v.w * v.w;
    }
    for (int off = 32; off; off >>= 1) s += __shfl_down(s, off);
    if (lane == 0) norms[row] = s;
}

// ---------------- codebook fp32 -> fp16, XOR-pre-swizzled for LDS staging ----------------
__global__ void vq_cvt_swz(const float* __restrict__ cb, unsigned short* __restrict__ eq) {
    int i = blockIdx.x * 256 + threadIdx.x;       // granule id (8 f16), NE*64 total
    int n = i >> 6, g = i & 63;
    int ch = g >> 4;
    int sl = (g & 15) ^ (n & 15);
    const float4* sp = (const float4*)(cb + (size_t)n * D + g * 8);
    float4 a = sp[0], b = sp[1];
    ushort4* dp = (ushort4*)(eq + (size_t)n * D + ch * KC + sl * 8);
    dp[0] = make_ushort4(f2h(a.x), f2h(a.y), f2h(a.z), f2h(a.w));
    dp[1] = make_ushort4(f2h(b.x), f2h(b.y), f2h(b.z), f2h(b.w));
}

// ---------------- fp16 MFMA distance, x-in-registers, per-lane top-2 ----------------
// grid 1024 = 256 rowblocks(128 rows) x 4 splits; block 256 thr (4 waves x 32 rows).
// Per phase: {vmcnt(0)[free] ; barrier ; STAGE(next) ; MFMA} -- prefetch crosses the
// barrier untouched (counted-wait discipline), STAGE-after-barrier closes the LDS WAR race.
__global__ __launch_bounds__(256, 2)
void vq_topk2(const float* __restrict__ x, const unsigned short* __restrict__ eq,
              const float* __restrict__ norms, float4* __restrict__ cands) {
    __shared__ char arena[40960];
    unsigned short* es0 = (unsigned short*)arena;            // 16 KB buffer A
    unsigned short* es1 = (unsigned short*)(arena + 16384);  // 16 KB buffer B
    float*          nlds = (float*)(arena + 32768);          // 8 KB split norms

    const int t = threadIdx.x;
    const int w = t >> 6, lane = t & 63, l15 = lane & 15, l4 = lane >> 4;
    const int b = blockIdx.x;
    const int xcd = b & 7;                 // blocks sharing an XCD share one eq slice
    const int sp  = xcd >> 1;
    const int rb  = ((b >> 3) << 1) | (xcd & 1);
    const size_t row0 = (size_t)rb * 128;
    const int nbase = sp * ESPAN;

#define STAGE(DST, STEP) do {                                                           \
        const int snt_ = (STEP) >> 2, sch_ = (STEP) & 3;                                \
        _Pragma("unroll")                                                               \
        for (int i_ = 0; i_ < 4; ++i_) {                                                \
            int c_ = i_ * 256 + t;                                                      \
            int row_ = c_ >> 4, sl_ = c_ & 15;                                          \
            g2l16(eq + (size_t)(nbase + snt_ * NT + row_) * D + sch_ * KC + sl_ * 8,    \
                  (DST) + (size_t)(i_ * 256 + w * 64) * 8);                             \
        }                                                                               \
    } while (0)

    // prologue: first e-chunk + norms -> LDS (all drained by first loop-top vmcnt(0))
    STAGE(es0, 0);
#pragma unroll
    for (int i = 0; i < 2; ++i) {
        int c = i * 256 + t;
        g2l16(norms + nbase + c * 4, (char*)nlds + (size_t)(i * 256 + w * 64) * 16);
    }

    // A fragments for this wave's 32 rows, full D, fused f32->f16
    f16x8 af[2][16];
#pragma unroll
    for (int mi = 0; mi < 2; ++mi) {
        const float4* xp = (const float4*)(x + (row0 + w * 32 + mi * 16 + l15) * D);
#pragma unroll
        for (int ks = 0; ks < 16; ++ks) {
            float4 p0 = xp[ks * 8 + l4 * 2];
            float4 p1 = xp[ks * 8 + l4 * 2 + 1];
            f16x8 v;
            v[0] = (_Float16)p0.x; v[1] = (_Float16)p0.y;
            v[2] = (_Float16)p0.z; v[3] = (_Float16)p0.w;
            v[4] = (_Float16)p1.x; v[5] = (_Float16)p1.y;
            v[6] = (_Float16)p1.z; v[7] = (_Float16)p1.w;
            af[mi][ks] = v;
        }
    }

    float v1[8], v2[8];
    int   i1[8], i2[8];
#pragma unroll
    for (int s = 0; s < 8; ++s) { v1[s] = v2[s] = 3.4e38f; i1[s] = i2[s] = 0x7fffffff; }

    unsigned short* cur = es0;
    unsigned short* nxt = es1;

    for (int nt_ = 0; nt_ < ESPAN / NT; ++nt_) {   // 32 entry tiles
        f32x4 acc[2][4];
#pragma unroll
        for (int mi = 0; mi < 2; ++mi)
#pragma unroll
            for (int ni = 0; ni < 4; ++ni) acc[mi][ni] = (f32x4){0.f, 0.f, 0.f, 0.f};

#pragma unroll
        for (int ch = 0; ch < 4; ++ch) {
            const int step = nt_ * 4 + ch;
            // cur-buffer loads were issued one full phase ago -> this wait is ~free
            asm volatile("s_waitcnt vmcnt(0)" ::: "memory");
            __builtin_amdgcn_s_barrier();
            __builtin_amdgcn_sched_barrier(0);   // nothing crosses the barrier
            if (step + 1 < NPHASE) STAGE(nxt, step + 1);   // prefetch flies over MFMA
            __builtin_amdgcn_s_setprio(1);
#pragma unroll
            for (int ksb = 0; ksb < 4; ++ksb) {
                f16x8 bfr[4];
#pragma unroll
                for (int ni = 0; ni < 4; ++ni) {
                    int slot = ((ksb << 2) | l4) ^ l15;      // XOR de-swizzle on read
                    bfr[ni] = *(const f16x8*)((const char*)cur + ni * 4096 + l15 * 256 + slot * 16);
                }
#pragma unroll
                for (int mi = 0; mi < 2; ++mi)
#pragma unroll
                    for (int ni = 0; ni < 4; ++ni)
                        acc[mi][ni] = __builtin_amdgcn_mfma_f32_16x16x32_f16(
                            af[mi][ch * 4 + ksb], bfr[ni], acc[mi][ni], 0, 0, 0);
            }
            __builtin_amdgcn_s_setprio(0);
            unsigned short* tswap = cur; cur = nxt; nxt = tswap;
        }

        // per-entry top-2 update (no tile-min: same-lane near-ties must both survive)
        const int n0 = nbase + nt_ * NT;
        float nn[4];
#pragma unroll
        for (int ni = 0; ni < 4; ++ni) nn[ni] = nlds[nt_ * 64 + ni * 16 + l15];
#pragma unroll
        for (int mi = 0; mi < 2; ++mi)
#pragma unroll
            for (int r = 0; r < 4; ++r) {
                int s = mi * 4 + r;
#pragma unroll
                for (int ni = 0; ni < 4; ++ni) {
                    float dd = fmaf(-2.f, acc[mi][ni][r], nn[ni]);
                    int   cc = n0 + ni * 16 + l15;
                    if (dd < v2[s]) {
                        bool b1 = dd < v1[s];
                        v2[s] = b1 ? v1[s] : dd; i2[s] = b1 ? i1[s] : cc;
                        v1[s] = b1 ? dd : v1[s]; i1[s] = b1 ? cc : i1[s];
                    }
                }
            }
    }
#undef STAGE

    // raw per-lane top-2 out: cands[row][sp*16 + l15] = (v1,i1,v2,i2)
#pragma unroll
    for (int s = 0; s < 8; ++s) {
        int mi = s >> 2, r = s & 3;
        size_t rowc = row0 + w * 32 + mi * 16 + l4 * 4 + r;
        cands[rowc * 64 + sp * 16 + l15] =
            make_float4(v1[s], __int_as_float(i1[s]), v2[s], __int_as_float(i2[s]));
    }
}

// ---------------- fused: merge cands + exact rescore + STE out + loss partials ----------------
__global__ __launch_bounds__(512)
void vq_finish(const float* __restrict__ x, const float* __restrict__ cb,
               const float* __restrict__ norms, const float4* __restrict__ cands,
               float* __restrict__ counts, float* __restrict__ psum, float* __restrict__ out) {
    __shared__ float red[8];
    const int t = threadIdx.x, w = t >> 6, lane = t & 63;
    const size_t row = (size_t)blockIdx.x * 8 + w;

    float4 c4 = cands[row * 64 + lane];
    float va = c4.x, vb = c4.z;
    int   ia = __float_as_int(c4.y), ib = __float_as_int(c4.w);
    float m = fminf(va, vb);
#pragma unroll
    for (int off = 1; off < 64; off <<= 1) m = fminf(m, __shfl_xor(m, off));
    const float thr = m + MARGIN;

    const float4* xp = (const float4*)(x + row * D);
    float4 xa = xp[lane * 2], xb = xp[lane * 2 + 1];

    float bd = 3.4e38f; int bi = 0x7fffffff;
#pragma unroll 1
    for (int q = 0; q < 2; ++q) {
        unsigned long long mk = __ballot((q == 0 ? va : vb) <= thr);
        while (mk) {
            int src = __builtin_ctzll(mk);
            mk &= mk - 1;
            int ci = __shfl(q == 0 ? ia : ib, src);
            const float4* ep = (const float4*)(cb + (size_t)ci * D);
            float4 ea = ep[lane * 2], eb = ep[lane * 2 + 1];
            float s = 0.f;
            s = fmaf(xa.x, ea.x, s); s = fmaf(xa.y, ea.y, s);
            s = fmaf(xa.z, ea.z, s); s = fmaf(xa.w, ea.w, s);
            s = fmaf(xb.x, eb.x, s); s = fmaf(xb.y, eb.y, s);
            s = fmaf(xb.z, eb.z, s); s = fmaf(xb.w, eb.w, s);
#pragma unroll
            for (int off = 1; off < 64; off <<= 1) s += __shfl_xor(s, off);
            float dd = fmaf(-2.f, s, norms[ci]);
            if (dd < bd || (dd == bd && ci < bi)) { bd = dd; bi = ci; }
        }
    }

    const float4* qp = (const float4*)(cb + (size_t)bi * D);
    float4 qa = qp[lane * 2], qb = qp[lane * 2 + 1];
    float4* op = (float4*)(out + row * D);
    float s2 = 0.f;
    float4 oa, ob;
    {
        float d0 = qa.x - xa.x; oa.x = xa.x + d0; s2 = fmaf(d0, d0, s2);
        float d1 = qa.y - xa.y; oa.y = xa.y + d1; s2 = fmaf(d1, d1, s2);
        float d2 = qa.z - xa.z; oa.z = xa.z + d2; s2 = fmaf(d2, d2, s2);
        float d3 = qa.w - xa.w; oa.w = xa.w + d3; s2 = fmaf(d3, d3, s2);
        float d4 = qb.x - xb.x; ob.x = xb.x + d4; s2 = fmaf(d4, d4, s2);
        float d5 = qb.y - xb.y; ob.y = xb.y + d5; s2 = fmaf(d5, d5, s2);
        float d6 = qb.z - xb.z; ob.z = xb.z + d6; s2 = fmaf(d6, d6, s2);
        float d7 = qb.w - xb.w; ob.w = xb.w + d7; s2 = fmaf(d7, d7, s2);
    }
    op[lane * 2] = oa; op[lane * 2 + 1] = ob;
    for (int off = 32; off; off >>= 1) s2 += __shfl_down(s2, off);
    if (lane == 0) {
        red[w] = s2;
        atomicAdd(&counts[bi], 1.0f);
    }
    __syncthreads();
    if (t == 0) {
        float s = 0.f;
#pragma unroll
        for (int i = 0; i < 8; ++i) s += red[i];
        psum[blockIdx.x] = s;
    }
}

// ---------------- loss + perplexity ----------------
__global__ void vq_finalize_kernel(const float* __restrict__ counts, const float* __restrict__ psum,
                                   float* __restrict__ out2) {
    __shared__ float rede[256];
    __shared__ float reds[256];
    float se = 0.f, ss = 0.f;
    for (int i = threadIdx.x; i < NE; i += 256) {
        float p = counts[i] * (1.0f / (float)BATCH);
        se += p * logf(p + 1e-10f);
    }
    for (int i = threadIdx.x; i < 4096; i += 256) ss += psum[i];
    rede[threadIdx.x] = se; reds[threadIdx.x] = ss;
    __syncthreads();
    for (int off = 128; off; off >>= 1) {
        if (threadIdx.x < off) {
            rede[threadIdx.x] += rede[threadIdx.x + off];
            reds[threadIdx.x] += reds[threadIdx.x + off];
        }
        __syncthreads();
    }
    if (threadIdx.x == 0) {
        out2[0] = 1.25f * reds[0] * (1.0f / (float)((size_t)BATCH * D));
        out2[1] = expf(-rede[0]);
    }
}

// ---------------- fallback fp32 path (round-1, known-good) ----------------
#define BM 64
#define BN 64
#define BK 16
#define LDSP 68
__global__ __launch_bounds__(256)
void vq_argmin_kernel(const float* __restrict__ x, const float* __restrict__ cb,
                      const float* __restrict__ norms, int* __restrict__ out_idx) {
    __shared__ float xs[BK * LDSP];
    __shared__ float es[BK * LDSP];
    __shared__ float rv[BM][16];
    __shared__ int   ri[BM][16];
    const int t = threadIdx.x, tx = t & 15, ty = t >> 4;
    const int row0 = blockIdx.x * BM, ldrow = t >> 2, ldq = t & 3;
    float minv[4]; int mini[4];
#pragma unroll
    for (int i = 0; i < 4; ++i) { minv[i] = 3.4e38f; mini[i] = 0; }
    for (int n0 = 0; n0 < NE; n0 += BN) {
        float acc[4][4];
#pragma unroll
        for (int i = 0; i < 4; ++i)
#pragma unroll
            for (int j = 0; j < 4; ++j) acc[i][j] = 0.f;
        for (int kk = 0; kk < D; kk += BK) {
            __syncthreads();
            float4 xv = *(const float4*)&x [(size_t)(row0 + ldrow) * D + kk + ldq * 4];
            float4 ev = *(const float4*)&cb[(size_t)(n0   + ldrow) * D + kk + ldq * 4];
            const float* xvp = (const float*)&xv;
            const float* evp = (const float*)&ev;
#pragma unroll
            for (int j = 0; j < 4; ++j) {
                xs[(ldq * 4 + j) * LDSP + ldrow] = xvp[j];
                es[(ldq * 4 + j) * LDSP + ldrow] = evp[j];
            }
            __syncthreads();
#pragma unroll
            for (int k = 0; k < BK; ++k) {
                float4 xr4 = *(const float4*)&xs[k * LDSP + ty * 4];
                float4 er4 = *(const float4*)&es[k * LDSP + tx * 4];
                const float xr[4] = {xr4.x, xr4.y, xr4.z, xr4.w};
                const float er[4] = {er4.x, er4.y, er4.z, er4.w};
#pragma unroll
                for (int i = 0; i < 4; ++i)
#pragma unroll
                    for (int j = 0; j < 4; ++j)
                        acc[i][j] = fmaf(xr[i], er[j], acc[i][j]);
            }
        }
#pragma unroll
        for (int j = 0; j < 4; ++j) {
            int n = n0 + tx * 4 + j;
            float nnv = norms[n];
#pragma unroll
            for (int i = 0; i < 4; ++i) {
                float dd = fmaf(-2.f, acc[i][j], nnv);
                if (dd < minv[i]) { minv[i] = dd; mini[i] = n; }
            }
        }
    }
    __syncthreads();
#pragma unroll
    for (int i = 0; i < 4; ++i) { rv[ty * 4 + i][tx] = minv[i]; ri[ty * 4 + i][tx] = mini[i]; }
    __syncthreads();
    if (t < BM) {
        float bv = rv[t][0]; int bi = ri[t][0];
#pragma unroll
        for (int j = 1; j < 16; ++j) {
            float v = rv[t][j]; int iz = ri[t][j];
            if (v < bv || (v == bv && iz < bi)) { bv = v; bi = iz; }
        }
        out_idx[row0 + t] = bi;
    }
}

__global__ void vq_gather_kernel(const float* __restrict__ x, const float* __restrict__ cb,
                                 const int* __restrict__ idx, float* __restrict__ out,
                                 float* __restrict__ counts, float* __restrict__ psum) {
    const int b = blockIdx.x, lane = threadIdx.x;
    const int e = idx[b];
    const float4* xp = (const float4*)(x  + (size_t)b * D);
    const float4* qp = (const float4*)(cb + (size_t)e * D);
    float4*       op = (float4*)(out + (size_t)b * D);
    float s = 0.f;
#pragma unroll
    for (int i = 0; i < 2; ++i) {
        float4 xv = xp[lane + 64 * i];
        float4 qv = qp[lane + 64 * i];
        float4 ov;
        float dx = qv.x - xv.x; ov.x = xv.x + dx; s = fmaf(dx, dx, s);
        float dy = qv.y - xv.y; ov.y = xv.y + dy; s = fmaf(dy, dy, s);
        float dz = qv.z - xv.z; ov.z = xv.z + dz; s = fmaf(dz, dz, s);
        float dw = qv.w - xv.w; ov.w = xv.w + dw; s = fmaf(dw, dw, s);
        op[lane + 64 * i] = ov;
    }
    for (int off = 32; off; off >>= 1) s += __shfl_down(s, off);
    if (lane == 0) {
        atomicAdd(&psum[0], s);
        atomicAdd(&counts[e], 1.0f);
    }
}

extern "C" void kernel_launch(void* const* d_in, const int* in_sizes, int n_in,
                              void* d_out, int out_size, void* d_ws, size_t ws_size,
                              hipStream_t stream) {
    const float* x  = (const float*)d_in[0];
    const float* cb = (const float*)d_in[1];
    float* out = (float*)d_out;

    char* ws = (char*)d_ws;
    float*  norms  = (float*)ws;                             // 32 KB @ 0
    float*  counts = (float*)(ws + 32768);                   // 32 KB
    float*  psum   = (float*)(ws + 65536);                   // 16 KB (4096 partials)
    int*    idx    = (int*)(ws + 81920);                     // 128 KB (fallback only)
    float4* cands  = (float4*)(ws + 262144);                 // 32 MB (32768 x 64 x 16B)
    unsigned short* eq = (unsigned short*)(ws + 33816576);   // 8 MB fp16 swizzled codebook
    const size_t WS_NEED = 42205184;

    hipMemsetAsync(counts, 0, NE * sizeof(float), stream);
    vq_norms_kernel<<<NE / 4, 256, 0, stream>>>(cb, norms);

    if (ws_size >= WS_NEED) {
        vq_cvt_swz<<<NE * 64 / 256, 256, 0, stream>>>(cb, eq);
        vq_topk2<<<1024, 256, 0, stream>>>(x, eq, norms, cands);
        vq_finish<<<BATCH / 8, 512, 0, stream>>>(x, cb, norms, cands, counts, psum, out);
    } else {
        hipMemsetAsync(psum, 0, 4096 * sizeof(float), stream);
        vq_argmin_kernel<<<BATCH / BM, 256, 0, stream>>>(x, cb, norms, idx);
        vq_gather_kernel<<<BATCH, 64, 0, stream>>>(x, cb, idx, out, counts, psum);
    }
    vq_finalize_kernel<<<1, 256, 0, stream>>>(counts, psum, out + (size_t)BATCH * D);
}